// Round 1
// baseline (594.565 us; speedup 1.0000x reference)
//
#include <hip/hip_runtime.h>

// Fused 2-layer LSTM (B=4096, S=512, H=64) + dense(64->32 relu)->dense(32->24).
// One WG = 256 threads = 4 waves handles a 16-row batch tile for all 512 steps.
// Wave w owns, for each gate g in {i,f,g,o}, h-columns [16w,16w+16): so the
// MFMA C/D layout (col=lane&15, row=quad*4+reg) makes the c/h update lane-local.
// Recurrent weights held in registers as MFMA B-fragments for all 512 steps.
// h1/h2 round-trip through padded LDS (bf16) between waves; 2 barriers/step.

typedef __attribute__((ext_vector_type(8))) short bf16x8;
typedef __attribute__((ext_vector_type(4))) float floatx4;

#define SEQ 512
#define HID 64

__device__ inline floatx4 MFMA(bf16x8 a, bf16x8 b, floatx4 c) {
    return __builtin_amdgcn_mfma_f32_16x16x32_bf16(a, b, c, 0, 0, 0);
}

__device__ inline short f2bf(float f) {   // RNE float -> bf16 bits
    unsigned u = __builtin_bit_cast(unsigned, f);
    u += 0x7FFFu + ((u >> 16) & 1u);
    return (short)(u >> 16);
}

__device__ inline float sigm(float x) {
    return __builtin_amdgcn_rcpf(1.0f + __expf(-x));
}
__device__ inline float tanh_fast(float x) {
    return 2.0f * __builtin_amdgcn_rcpf(1.0f + __expf(-2.0f * x)) - 1.0f;
}

__global__ __launch_bounds__(256, 1) void lstm_fused(
    const float* __restrict__ x,
    const float* __restrict__ Wih1, const float* __restrict__ Whh1,
    const float* __restrict__ bih1, const float* __restrict__ bhh1,
    const float* __restrict__ Wih2, const float* __restrict__ Whh2,
    const float* __restrict__ bih2, const float* __restrict__ bhh2,
    const float* __restrict__ Wd1,  const float* __restrict__ bd1,
    const float* __restrict__ Wd2,  const float* __restrict__ bd2,
    float* __restrict__ out)
{
    const int tid  = threadIdx.x;
    const int wave = tid >> 6;
    const int lane = tid & 63;
    const int l15  = lane & 15;
    const int quad = lane >> 4;
    const int b0   = blockIdx.x * 16;

    __shared__ __align__(16) float x_s[16][516];   // +4 pad: 16B-aligned rows, no bank clash
    __shared__ __align__(16) short h1_s[16][72];   // +8 pad: conflict-free b128 A-frag reads
    __shared__ __align__(16) short h2_s[16][72];
    __shared__ float y1_s[16][32];

    // ---- stage x tile (16 rows x 512 f32) ----
    {
        const int row = tid >> 4;
        const int c0  = (tid & 15) * 32;
        const float4* src = reinterpret_cast<const float4*>(x + (size_t)(b0 + row) * SEQ + c0);
        float4* dst = reinterpret_cast<float4*>(&x_s[row][c0]);
        #pragma unroll
        for (int j = 0; j < 8; ++j) dst[j] = src[j];
    }
    for (int i = tid; i < 16 * 72; i += 256) {     // h1[-1] = h2[-1] = 0
        (&h1_s[0][0])[i] = 0;
        (&h2_s[0][0])[i] = 0;
    }

    // ---- weight B-fragments (held in registers for the whole scan) ----
    // B[k][n]: lane holds n = lane&15 (within 16-col tile), k = quad*8+j.
    bf16x8 Bhh1[2][4], Bih2[2][4], Bhh2[2][4];     // [ktile][gate]
    float wih1c[4], b1c[4], b2c[4];
    #pragma unroll
    for (int g = 0; g < 4; ++g) {
        const int col = g * 64 + wave * 16 + l15;  // gate-output row of W matrices
        wih1c[g] = Wih1[col];                       // W_ih1 is [256][1]
        b1c[g]   = bih1[col] + bhh1[col];
        b2c[g]   = bih2[col] + bhh2[col];
        #pragma unroll
        for (int kt = 0; kt < 2; ++kt) {
            const int koff = kt * 32 + quad * 8;
            union { short s[8]; bf16x8 v; } u1, u2, u3;
            #pragma unroll
            for (int j = 0; j < 8; ++j) {
                u1.s[j] = f2bf(Whh1[col * HID + koff + j]);
                u2.s[j] = f2bf(Wih2[col * HID + koff + j]);
                u3.s[j] = f2bf(Whh2[col * HID + koff + j]);
            }
            Bhh1[kt][g] = u1.v; Bih2[kt][g] = u2.v; Bhh2[kt][g] = u3.v;
        }
    }

    const int hcol = wave * 16 + l15;              // this lane's hidden-unit column
    const short* a1p0 = &h1_s[l15][quad * 8];      // A[m=l15][k=quad*8+j]
    const short* a1p1 = &h1_s[l15][32 + quad * 8];
    const short* a2p0 = &h2_s[l15][quad * 8];
    const short* a2p1 = &h2_s[l15][32 + quad * 8];

    float c1[4] = {0, 0, 0, 0}, c2[4] = {0, 0, 0, 0};
    floatx4 z2[4];                                  // carries b2 + Whh2 @ h2[t-2] into iter t
    #pragma unroll
    for (int g = 0; g < 4; ++g) z2[g] = floatx4{b2c[g], b2c[g], b2c[g], b2c[g]};

    for (int t = 0; t < SEQ; ++t) {
        __syncthreads();                            // h1_s == h1[t-1]
        const bf16x8 A1a = *reinterpret_cast<const bf16x8*>(a1p0);
        const bf16x8 A1b = *reinterpret_cast<const bf16x8*>(a1p1);

        float xr[4];
        #pragma unroll
        for (int r = 0; r < 4; ++r) xr[r] = x_s[quad * 4 + r][t];

        floatx4 z1[4];
        #pragma unroll
        for (int g = 0; g < 4; ++g) {
            floatx4 zi;
            #pragma unroll
            for (int r = 0; r < 4; ++r) zi[r] = xr[r] * wih1c[g] + b1c[g];
            zi = MFMA(A1a, Bhh1[0][g], zi);         // z1[t]
            zi = MFMA(A1b, Bhh1[1][g], zi);
            z1[g] = zi;
            z2[g] = MFMA(A1a, Bih2[0][g], z2[g]);   // completes z2[t-1]
            z2[g] = MFMA(A1b, Bih2[1][g], z2[g]);
        }

        if (t > 0) {                                // layer-2 gates for step t-1
            float h2v[4];
            #pragma unroll
            for (int r = 0; r < 4; ++r) {
                float ig = sigm(z2[0][r]);
                float fg = sigm(z2[1][r]);
                float gg = tanh_fast(z2[2][r]);
                float og = sigm(z2[3][r]);
                float c  = fg * c2[r] + ig * gg;
                c2[r] = c;
                h2v[r] = og * tanh_fast(c);
            }
            #pragma unroll
            for (int r = 0; r < 4; ++r)
                h2_s[quad * 4 + r][hcol] = f2bf(h2v[r]);
        }

        float h1v[4];                               // layer-1 gates for step t
        #pragma unroll
        for (int r = 0; r < 4; ++r) {
            float ig = sigm(z1[0][r]);
            float fg = sigm(z1[1][r]);
            float gg = tanh_fast(z1[2][r]);
            float og = sigm(z1[3][r]);
            float c  = fg * c1[r] + ig * gg;
            c1[r] = c;
            h1v[r] = og * tanh_fast(c);
        }

        __syncthreads();                            // h2_s == h2[t-1]; all h1 reads done
        const bf16x8 A2a = *reinterpret_cast<const bf16x8*>(a2p0);
        const bf16x8 A2b = *reinterpret_cast<const bf16x8*>(a2p1);
        #pragma unroll
        for (int g = 0; g < 4; ++g) {
            floatx4 zi;
            #pragma unroll
            for (int r = 0; r < 4; ++r) zi[r] = b2c[g];
            zi = MFMA(A2a, Bhh2[0][g], zi);         // b2 + Whh2 @ h2[t-1], for next iter
            zi = MFMA(A2b, Bhh2[1][g], zi);
            z2[g] = zi;
        }
        #pragma unroll
        for (int r = 0; r < 4; ++r)
            h1_s[quad * 4 + r][hcol] = f2bf(h1v[r]);
    }

    // ---- drain: finish layer 2 for t = SEQ-1 ----
    __syncthreads();                                // h1_s == h1[S-1]
    {
        const bf16x8 A1a = *reinterpret_cast<const bf16x8*>(a1p0);
        const bf16x8 A1b = *reinterpret_cast<const bf16x8*>(a1p1);
        #pragma unroll
        for (int g = 0; g < 4; ++g) {
            z2[g] = MFMA(A1a, Bih2[0][g], z2[g]);
            z2[g] = MFMA(A1b, Bih2[1][g], z2[g]);
        }
        float* h2f = &x_s[0][0];                    // repurpose x stage as [16][64] f32
        #pragma unroll
        for (int r = 0; r < 4; ++r) {
            float ig = sigm(z2[0][r]);
            float fg = sigm(z2[1][r]);
            float gg = tanh_fast(z2[2][r]);
            float og = sigm(z2[3][r]);
            float c  = fg * c2[r] + ig * gg;
            h2f[(quad * 4 + r) * HID + hcol] = og * tanh_fast(c);
        }
    }
    __syncthreads();

    // ---- epilogue: relu(h2 @ Wd1^T + bd1) @ Wd2^T + bd2 ----
    const float* h2f = &x_s[0][0];
    for (int idx = tid; idx < 16 * 32; idx += 256) {
        const int b = idx >> 5, o = idx & 31;
        float acc = bd1[o];
        #pragma unroll 8
        for (int k = 0; k < HID; ++k) acc += h2f[b * HID + k] * Wd1[o * HID + k];
        y1_s[b][o] = fmaxf(acc, 0.0f);
    }
    __syncthreads();
    for (int idx = tid; idx < 16 * 24; idx += 256) {
        const int b = idx / 24, o = idx - b * 24;
        float acc = bd2[o];
        #pragma unroll 8
        for (int k = 0; k < 32; ++k) acc += y1_s[b][k] * Wd2[o * 32 + k];
        out[(size_t)(b0 + b) * 24 + o] = acc;
    }
}

extern "C" void kernel_launch(void* const* d_in, const int* in_sizes, int n_in,
                              void* d_out, int out_size, void* d_ws, size_t ws_size,
                              hipStream_t stream) {
    const float* x    = (const float*)d_in[0];
    const float* Wih1 = (const float*)d_in[1];
    const float* Whh1 = (const float*)d_in[2];
    const float* bih1 = (const float*)d_in[3];
    const float* bhh1 = (const float*)d_in[4];
    const float* Wih2 = (const float*)d_in[5];
    const float* Whh2 = (const float*)d_in[6];
    const float* bih2 = (const float*)d_in[7];
    const float* bhh2 = (const float*)d_in[8];
    const float* Wd1  = (const float*)d_in[9];
    const float* bd1  = (const float*)d_in[10];
    const float* Wd2  = (const float*)d_in[11];
    const float* bd2  = (const float*)d_in[12];
    float* out = (float*)d_out;

    lstm_fused<<<256, 256, 0, stream>>>(x, Wih1, Whh1, bih1, bhh1,
                                        Wih2, Whh2, bih2, bhh2,
                                        Wd1, bd1, Wd2, bd2, out);
}

// Round 2
// 507.530 us; speedup vs baseline: 1.1715x; 1.1715x over previous
//
#include <hip/hip_runtime.h>

// Fused 2-layer LSTM (B=4096, S=512, H=64) + dense(64->32 relu)->dense(32->24).
// One WG = 256 thr = 4 waves per 16-row batch tile, grid = 256 = 1 WG/CU.
// R2 changes vs R1:
//  - ONE barrier/step: parity double-buffered h1/h2 in LDS; layer-2 delayed one
//    step so z2[t-1] = b2 + Wih2@h1[t-1] + Whh2@h2[t-2] — all operands committed
//    before the top-of-loop barrier; h1[t-1] A-frag shared by Whh1 and Wih2.
//  - trans ops 10 -> 8 per element: merged rcp for sigm(i)*tanh(g) and
//    sigm(o)*tanh(c); only e^{-2c} arg clamped (c is the only unbounded input).
//  - -log2e (gate g: -2log2e) folded into weights/biases: v_exp_f32 args need
//    zero prep. bf16 store cvt via native __bf16 cast.

typedef __attribute__((ext_vector_type(8))) short bf16x8;
typedef __attribute__((ext_vector_type(4))) float floatx4;

#define SEQ 512
#define HID 64
#define LOG2E 1.4426950408889634f

__device__ inline floatx4 MFMA(bf16x8 a, bf16x8 b, floatx4 c) {
    return __builtin_amdgcn_mfma_f32_16x16x32_bf16(a, b, c, 0, 0, 0);
}
__device__ inline short f2bf(float f) {
    __bf16 b = (__bf16)f;                      // fptrunc RNE -> v_cvt_pk_bf16_f32
    return __builtin_bit_cast(short, b);
}
__device__ inline float exp2_fast(float x) {
#if __has_builtin(__builtin_amdgcn_exp2f)
    return __builtin_amdgcn_exp2f(x);
#else
    return __expf(x * 0.6931471805599453f);
#endif
}
__device__ inline float rcp_fast(float x) { return __builtin_amdgcn_rcpf(x); }

// z* are pre-scaled: zi=-i*log2e, zf=-f*log2e, zg=-2g*log2e, zo=-o*log2e.
// Returns h = sigm(o)*tanh(c'); updates c' = sigm(f)*c + sigm(i)*tanh(g).
__device__ inline float lstm_gate(float zi, float zf, float zg, float zo, float& c) {
    float ei = exp2_fast(zi);
    float ef = exp2_fast(zf);
    float eg = exp2_fast(zg);
    float eo = exp2_fast(zo);
    float sf = rcp_fast(1.0f + ef);                              // sigm(f)
    float ig = (1.0f - eg) * rcp_fast((1.0f + ei) * (1.0f + eg)); // sigm(i)*tanh(g)
    c = sf * c + ig;
    float ec = exp2_fast(fminf(c * (-2.0f * LOG2E), 40.0f));     // e^{-2c}, clamped
    return (1.0f - ec) * rcp_fast((1.0f + eo) * (1.0f + ec));    // sigm(o)*tanh(c)
}

__global__ __launch_bounds__(256, 1) void lstm_fused(
    const float* __restrict__ x,
    const float* __restrict__ Wih1, const float* __restrict__ Whh1,
    const float* __restrict__ bih1, const float* __restrict__ bhh1,
    const float* __restrict__ Wih2, const float* __restrict__ Whh2,
    const float* __restrict__ bih2, const float* __restrict__ bhh2,
    const float* __restrict__ Wd1,  const float* __restrict__ bd1,
    const float* __restrict__ Wd2,  const float* __restrict__ bd2,
    float* __restrict__ out)
{
    const int tid  = threadIdx.x;
    const int wave = tid >> 6;
    const int lane = tid & 63;
    const int l15  = lane & 15;
    const int quad = lane >> 4;
    const int b0   = blockIdx.x * 16;

    __shared__ __align__(16) float x_s[16][516];     // 33 KB (rows 16B-aligned)
    __shared__ __align__(16) short h1_s[2][16][72];  // parity double buffer
    __shared__ __align__(16) short h2_s[2][16][72];
    __shared__ float y1_s[16][32];

    // ---- stage x tile ----
    {
        const int row = tid >> 4;
        const int c0  = (tid & 15) * 32;
        const float4* src = reinterpret_cast<const float4*>(x + (size_t)(b0 + row) * SEQ + c0);
        float4* dst = reinterpret_cast<float4*>(&x_s[row][c0]);
        #pragma unroll
        for (int j = 0; j < 8; ++j) dst[j] = src[j];
    }
    for (int i = tid; i < 2 * 16 * 72; i += 256) {   // h1[-1]=h2[-1]=h2[-2]=0
        (&h1_s[0][0][0])[i] = 0;
        (&h2_s[0][0][0])[i] = 0;
    }

    // ---- weight B-fragments, pre-scaled by -log2e (gate g: -2log2e) ----
    bf16x8 Bhh1[2][4], Bih2[2][4], Bhh2[2][4];
    float wih1c[4], b1c[4], b2c[4];
    #pragma unroll
    for (int g = 0; g < 4; ++g) {
        const float sc = (g == 2) ? (-2.0f * LOG2E) : (-LOG2E);
        const int col = g * 64 + wave * 16 + l15;
        wih1c[g] = Wih1[col] * sc;
        b1c[g]   = (bih1[col] + bhh1[col]) * sc;
        b2c[g]   = (bih2[col] + bhh2[col]) * sc;
        #pragma unroll
        for (int kt = 0; kt < 2; ++kt) {
            const int koff = kt * 32 + quad * 8;
            union { short s[8]; bf16x8 v; } u1, u2, u3;
            #pragma unroll
            for (int j = 0; j < 8; ++j) {
                u1.s[j] = f2bf(Whh1[col * HID + koff + j] * sc);
                u2.s[j] = f2bf(Wih2[col * HID + koff + j] * sc);
                u3.s[j] = f2bf(Whh2[col * HID + koff + j] * sc);
            }
            Bhh1[kt][g] = u1.v; Bih2[kt][g] = u2.v; Bhh2[kt][g] = u3.v;
        }
    }

    const int hcol = wave * 16 + l15;
    float c1[4] = {0, 0, 0, 0}, c2[4] = {0, 0, 0, 0};

    #pragma unroll 2
    for (int t = 0; t < SEQ; ++t) {
        const int pr1 = (t + 1) & 1;   // h1[t-1] lives here; h2[t-1] written here
        const int pr2 = t & 1;         // h2[t-2] lives here; h1[t] written here
        __syncthreads();
        const bf16x8 A1a = *reinterpret_cast<const bf16x8*>(&h1_s[pr1][l15][quad * 8]);
        const bf16x8 A1b = *reinterpret_cast<const bf16x8*>(&h1_s[pr1][l15][32 + quad * 8]);
        const bf16x8 A2a = *reinterpret_cast<const bf16x8*>(&h2_s[pr2][l15][quad * 8]);
        const bf16x8 A2b = *reinterpret_cast<const bf16x8*>(&h2_s[pr2][l15][32 + quad * 8]);

        floatx4 z1[4], z2[4];
        #pragma unroll
        for (int g = 0; g < 4; ++g) {
            #pragma unroll
            for (int r = 0; r < 4; ++r)
                z1[g][r] = x_s[quad * 4 + r][t] * wih1c[g] + b1c[g];
            z2[g] = floatx4{b2c[g], b2c[g], b2c[g], b2c[g]};
        }
        #pragma unroll
        for (int g = 0; g < 4; ++g) {
            z1[g] = MFMA(A1a, Bhh1[0][g], z1[g]);   // z1[t]
            z1[g] = MFMA(A1b, Bhh1[1][g], z1[g]);
            z2[g] = MFMA(A1a, Bih2[0][g], z2[g]);   // z2[t-1]
            z2[g] = MFMA(A1b, Bih2[1][g], z2[g]);
            z2[g] = MFMA(A2a, Bhh2[0][g], z2[g]);
            z2[g] = MFMA(A2b, Bhh2[1][g], z2[g]);
        }

        const float m2 = (t == 0) ? 0.0f : 1.0f;    // discard bogus layer-2 step at t=0
        #pragma unroll
        for (int r = 0; r < 4; ++r) {
            float h1v = lstm_gate(z1[0][r], z1[1][r], z1[2][r], z1[3][r], c1[r]);
            h1_s[pr2][quad * 4 + r][hcol] = f2bf(h1v);            // h1[t] -> buf t&1
            float cc = c2[r];
            float h2v = lstm_gate(z2[0][r], z2[1][r], z2[2][r], z2[3][r], cc) * m2;
            c2[r] = cc * m2;
            h2_s[pr1][quad * 4 + r][hcol] = f2bf(h2v);            // h2[t-1] -> buf (t-1)&1
        }
    }

    // ---- drain: layer 2 for t = SEQ-1 ----
    __syncthreads();
    {
        const bf16x8 A1a = *reinterpret_cast<const bf16x8*>(&h1_s[1][l15][quad * 8]);      // h1[511]
        const bf16x8 A1b = *reinterpret_cast<const bf16x8*>(&h1_s[1][l15][32 + quad * 8]);
        const bf16x8 A2a = *reinterpret_cast<const bf16x8*>(&h2_s[0][l15][quad * 8]);      // h2[510]
        const bf16x8 A2b = *reinterpret_cast<const bf16x8*>(&h2_s[0][l15][32 + quad * 8]);
        floatx4 z2[4];
        #pragma unroll
        for (int g = 0; g < 4; ++g) {
            z2[g] = floatx4{b2c[g], b2c[g], b2c[g], b2c[g]};
            z2[g] = MFMA(A1a, Bih2[0][g], z2[g]);
            z2[g] = MFMA(A1b, Bih2[1][g], z2[g]);
            z2[g] = MFMA(A2a, Bhh2[0][g], z2[g]);
            z2[g] = MFMA(A2b, Bhh2[1][g], z2[g]);
        }
        float* h2f = &x_s[0][0];                    // repurpose x stage as [16][64] f32
        #pragma unroll
        for (int r = 0; r < 4; ++r) {
            float cc = c2[r];
            float h2v = lstm_gate(z2[0][r], z2[1][r], z2[2][r], z2[3][r], cc);
            h2f[(quad * 4 + r) * HID + hcol] = h2v;
        }
    }
    __syncthreads();

    // ---- epilogue: relu(h2 @ Wd1^T + bd1) @ Wd2^T + bd2 ----
    const float* h2f = &x_s[0][0];
    for (int idx = tid; idx < 16 * 32; idx += 256) {
        const int b = idx >> 5, o = idx & 31;
        float acc = bd1[o];
        #pragma unroll 8
        for (int k = 0; k < HID; ++k) acc += h2f[b * HID + k] * Wd1[o * HID + k];
        y1_s[b][o] = fmaxf(acc, 0.0f);
    }
    __syncthreads();
    for (int idx = tid; idx < 16 * 24; idx += 256) {
        const int b = idx / 24, o = idx - b * 24;
        float acc = bd2[o];
        #pragma unroll 8
        for (int k = 0; k < 32; ++k) acc += y1_s[b][k] * Wd2[o * 32 + k];
        out[(size_t)(b0 + b) * 24 + o] = acc;
    }
}

extern "C" void kernel_launch(void* const* d_in, const int* in_sizes, int n_in,
                              void* d_out, int out_size, void* d_ws, size_t ws_size,
                              hipStream_t stream) {
    const float* x    = (const float*)d_in[0];
    const float* Wih1 = (const float*)d_in[1];
    const float* Whh1 = (const float*)d_in[2];
    const float* bih1 = (const float*)d_in[3];
    const float* bhh1 = (const float*)d_in[4];
    const float* Wih2 = (const float*)d_in[5];
    const float* Whh2 = (const float*)d_in[6];
    const float* bih2 = (const float*)d_in[7];
    const float* bhh2 = (const float*)d_in[8];
    const float* Wd1  = (const float*)d_in[9];
    const float* bd1  = (const float*)d_in[10];
    const float* Wd2  = (const float*)d_in[11];
    const float* bd2  = (const float*)d_in[12];
    float* out = (float*)d_out;

    lstm_fused<<<256, 256, 0, stream>>>(x, Wih1, Whh1, bih1, bhh1,
                                        Wih2, Whh2, bih2, bhh2,
                                        Wd1, bd1, Wd2, bd2, out);
}

// Round 3
// 465.467 us; speedup vs baseline: 1.2774x; 1.0904x over previous
//
#include <hip/hip_runtime.h>

// Fused 2-layer LSTM (B=4096, S=512, H=64) + dense(64->32 relu)->dense(32->24).
// R3: 512-thread WG (8 waves, 2/SIMD) per 16-row batch tile, grid=256=1 WG/CU.
// Waves 0-3: layer-1 gates (col-tile = wave&3). Waves 4-7: layer-2 gates.
// Same total VALU work as R2, but MFMA + barrier stalls of one wave hide under
// the co-resident wave's VALU (m114: pipes co-schedule across waves).
// Single barrier/step via parity double-buffered h1/h2 (layer-2 delayed 1 step:
// z2[t-1] = b2 + Wih2@h1[t-1] + Whh2@h2[t-2]).
// Gate math: 5 exp + 2 rcp per element (i/f/g denominators merged).

typedef __attribute__((ext_vector_type(8))) short bf16x8;
typedef __attribute__((ext_vector_type(4))) float floatx4;

#define SEQ 512
#define HID 64
#define LOG2E 1.4426950408889634f

__device__ inline floatx4 MFMA(bf16x8 a, bf16x8 b, floatx4 c) {
    return __builtin_amdgcn_mfma_f32_16x16x32_bf16(a, b, c, 0, 0, 0);
}
__device__ inline short f2bf(float f) {
    __bf16 b = (__bf16)f;
    return __builtin_bit_cast(short, b);
}
__device__ inline float exp2_fast(float x) {
#if __has_builtin(__builtin_amdgcn_exp2f)
    return __builtin_amdgcn_exp2f(x);
#else
    return __expf(x * 0.6931471805599453f);
#endif
}
__device__ inline float rcp_fast(float x) { return __builtin_amdgcn_rcpf(x); }

// z* pre-scaled: zi=-i*log2e, zf=-f*log2e, zg=-2g*log2e, zo=-o*log2e.
// c' = [c*(1+ei)(1+eg) + (1-eg)(1+ef)] / [(1+ef)(1+ei)(1+eg)]  (merged rcp)
// h  = sigm(o)*tanh(c') = (1-ec)/((1+eo)(1+ec)),  ec = e^{-2c'} (clamped)
__device__ inline float lstm_gate(float zi, float zf, float zg, float zo, float& c) {
    float ei = exp2_fast(zi);
    float ef = exp2_fast(zf);
    float eg = exp2_fast(zg);
    float eo = exp2_fast(zo);
    float P  = (1.0f + ei) * (1.0f + eg);
    float F  = 1.0f + ef;
    float num = c * P + (1.0f - eg) * F;
    c = num * rcp_fast(P * F);
    float ec = exp2_fast(fminf(c * (-2.0f * LOG2E), 40.0f));
    return (1.0f - ec) * rcp_fast((1.0f + eo) * (1.0f + ec));
}

__global__ __launch_bounds__(512, 2) void lstm_fused(
    const float* __restrict__ x,
    const float* __restrict__ Wih1, const float* __restrict__ Whh1,
    const float* __restrict__ bih1, const float* __restrict__ bhh1,
    const float* __restrict__ Wih2, const float* __restrict__ Whh2,
    const float* __restrict__ bih2, const float* __restrict__ bhh2,
    const float* __restrict__ Wd1,  const float* __restrict__ bd1,
    const float* __restrict__ Wd2,  const float* __restrict__ bd2,
    float* __restrict__ out)
{
    const int tid  = threadIdx.x;
    const int wave = tid >> 6;
    const int ct   = wave & 3;       // column-tile (h-cols [16ct,16ct+16))
    const int is2  = wave >> 2;      // 0: layer-1 wave, 1: layer-2 wave
    const int lane = tid & 63;
    const int l15  = lane & 15;
    const int quad = lane >> 4;
    const int b0   = blockIdx.x * 16;

    __shared__ __align__(16) float x_s[16][516];
    __shared__ __align__(16) short h1_s[2][16][72];
    __shared__ __align__(16) short h2_s[2][16][72];
    __shared__ float y1_s[16][32];

    // ---- stage x tile (16 rows x 512 f32), 512 threads ----
    {
        const int row = tid >> 5;
        const int c0  = (tid & 31) * 16;
        const float4* src = reinterpret_cast<const float4*>(x + (size_t)(b0 + row) * SEQ + c0);
        float4* dst = reinterpret_cast<float4*>(&x_s[row][c0]);
        #pragma unroll
        for (int j = 0; j < 4; ++j) dst[j] = src[j];
    }
    for (int i = tid; i < 2 * 16 * 72; i += 512) {
        (&h1_s[0][0][0])[i] = 0;
        (&h2_s[0][0][0])[i] = 0;
    }

    // ---- per-wave weight B-fragments (pre-scaled by -log2e; gate g: -2log2e) ----
    // layer-1 waves: Wf[0..1] = Whh1 K-halves.  layer-2: Wf[0..1]=Wih2, Wf[2..3]=Whh2.
    bf16x8 Wf[4][4];
    float wxc[4], bcs[4];
    #pragma unroll
    for (int g = 0; g < 4; ++g) {
        const float sc = (g == 2) ? (-2.0f * LOG2E) : (-LOG2E);
        const int col = g * 64 + ct * 16 + l15;
        if (!is2) {
            wxc[g] = Wih1[col] * sc;
            bcs[g] = (bih1[col] + bhh1[col]) * sc;
        } else {
            wxc[g] = 0.0f;
            bcs[g] = (bih2[col] + bhh2[col]) * sc;
        }
        #pragma unroll
        for (int kt = 0; kt < 2; ++kt) {
            const int koff = kt * 32 + quad * 8;
            union { short s[8]; bf16x8 v; } u0, u1;
            #pragma unroll
            for (int j = 0; j < 8; ++j) {
                if (!is2) {
                    u0.s[j] = f2bf(Whh1[col * HID + koff + j] * sc);
                    u1.s[j] = 0;
                } else {
                    u0.s[j] = f2bf(Wih2[col * HID + koff + j] * sc);
                    u1.s[j] = f2bf(Whh2[col * HID + koff + j] * sc);
                }
            }
            Wf[kt][g] = u0.v;
            Wf[2 + kt][g] = u1.v;
        }
    }

    const int hcol = ct * 16 + l15;
    float cst[4] = {0, 0, 0, 0};

    #pragma unroll 2
    for (int t = 0; t < SEQ; ++t) {
        const int pr1 = (t + 1) & 1;   // holds h1[t-1] / receives h2[t-1]
        const int pr2 = t & 1;         // holds h2[t-2] / receives h1[t]
        __syncthreads();
        if (!is2) {
            const bf16x8 A1a = *reinterpret_cast<const bf16x8*>(&h1_s[pr1][l15][quad * 8]);
            const bf16x8 A1b = *reinterpret_cast<const bf16x8*>(&h1_s[pr1][l15][32 + quad * 8]);
            floatx4 z[4];
            #pragma unroll
            for (int g = 0; g < 4; ++g)
                #pragma unroll
                for (int r = 0; r < 4; ++r)
                    z[g][r] = x_s[quad * 4 + r][t] * wxc[g] + bcs[g];
            #pragma unroll
            for (int g = 0; g < 4; ++g) {
                z[g] = MFMA(A1a, Wf[0][g], z[g]);
                z[g] = MFMA(A1b, Wf[1][g], z[g]);
            }
            #pragma unroll
            for (int r = 0; r < 4; ++r) {
                float h1v = lstm_gate(z[0][r], z[1][r], z[2][r], z[3][r], cst[r]);
                h1_s[pr2][quad * 4 + r][hcol] = f2bf(h1v);
            }
        } else {
            const bf16x8 A1a = *reinterpret_cast<const bf16x8*>(&h1_s[pr1][l15][quad * 8]);
            const bf16x8 A1b = *reinterpret_cast<const bf16x8*>(&h1_s[pr1][l15][32 + quad * 8]);
            const bf16x8 A2a = *reinterpret_cast<const bf16x8*>(&h2_s[pr2][l15][quad * 8]);
            const bf16x8 A2b = *reinterpret_cast<const bf16x8*>(&h2_s[pr2][l15][32 + quad * 8]);
            floatx4 z[4];
            #pragma unroll
            for (int g = 0; g < 4; ++g)
                z[g] = floatx4{bcs[g], bcs[g], bcs[g], bcs[g]};
            #pragma unroll
            for (int g = 0; g < 4; ++g) {
                z[g] = MFMA(A1a, Wf[0][g], z[g]);   // Wih2 @ h1[t-1]
                z[g] = MFMA(A1b, Wf[1][g], z[g]);
                z[g] = MFMA(A2a, Wf[2][g], z[g]);   // Whh2 @ h2[t-2]
                z[g] = MFMA(A2b, Wf[3][g], z[g]);
            }
            const float m2 = (t == 0) ? 0.0f : 1.0f;  // discard bogus step at t=0
            #pragma unroll
            for (int r = 0; r < 4; ++r) {
                float cc = cst[r];
                float h2v = lstm_gate(z[0][r], z[1][r], z[2][r], z[3][r], cc) * m2;
                cst[r] = cc * m2;
                h2_s[pr1][quad * 4 + r][hcol] = f2bf(h2v);  // h2[t-1]
            }
        }
    }

    // ---- drain: layer 2 for t = SEQ-1 (layer-2 waves only) ----
    __syncthreads();
    if (is2) {
        const bf16x8 A1a = *reinterpret_cast<const bf16x8*>(&h1_s[1][l15][quad * 8]);       // h1[511]
        const bf16x8 A1b = *reinterpret_cast<const bf16x8*>(&h1_s[1][l15][32 + quad * 8]);
        const bf16x8 A2a = *reinterpret_cast<const bf16x8*>(&h2_s[0][l15][quad * 8]);       // h2[510]
        const bf16x8 A2b = *reinterpret_cast<const bf16x8*>(&h2_s[0][l15][32 + quad * 8]);
        floatx4 z[4];
        #pragma unroll
        for (int g = 0; g < 4; ++g) {
            z[g] = floatx4{bcs[g], bcs[g], bcs[g], bcs[g]};
            z[g] = MFMA(A1a, Wf[0][g], z[g]);
            z[g] = MFMA(A1b, Wf[1][g], z[g]);
            z[g] = MFMA(A2a, Wf[2][g], z[g]);
            z[g] = MFMA(A2b, Wf[3][g], z[g]);
        }
        float* h2f = &x_s[0][0];                    // repurpose x stage as [16][64] f32
        #pragma unroll
        for (int r = 0; r < 4; ++r) {
            float cc = cst[r];
            float h2v = lstm_gate(z[0][r], z[1][r], z[2][r], z[3][r], cc);
            h2f[(quad * 4 + r) * HID + hcol] = h2v;
        }
    }
    __syncthreads();

    // ---- epilogue: relu(h2 @ Wd1^T + bd1) @ Wd2^T + bd2 ----
    const float* h2f = &x_s[0][0];
    for (int idx = tid; idx < 16 * 32; idx += 512) {
        const int b = idx >> 5, o = idx & 31;
        float acc = bd1[o];
        #pragma unroll 8
        for (int k = 0; k < HID; ++k) acc += h2f[b * HID + k] * Wd1[o * HID + k];
        y1_s[b][o] = fmaxf(acc, 0.0f);
    }
    __syncthreads();
    for (int idx = tid; idx < 16 * 24; idx += 512) {
        const int b = idx / 24, o = idx - b * 24;
        float acc = bd2[o];
        #pragma unroll 8
        for (int k = 0; k < 32; ++k) acc += y1_s[b][k] * Wd2[o * 32 + k];
        out[(size_t)(b0 + b) * 24 + o] = acc;
    }
}

extern "C" void kernel_launch(void* const* d_in, const int* in_sizes, int n_in,
                              void* d_out, int out_size, void* d_ws, size_t ws_size,
                              hipStream_t stream) {
    const float* x    = (const float*)d_in[0];
    const float* Wih1 = (const float*)d_in[1];
    const float* Whh1 = (const float*)d_in[2];
    const float* bih1 = (const float*)d_in[3];
    const float* bhh1 = (const float*)d_in[4];
    const float* Wih2 = (const float*)d_in[5];
    const float* Whh2 = (const float*)d_in[6];
    const float* bih2 = (const float*)d_in[7];
    const float* bhh2 = (const float*)d_in[8];
    const float* Wd1  = (const float*)d_in[9];
    const float* bd1  = (const float*)d_in[10];
    const float* Wd2  = (const float*)d_in[11];
    const float* bd2  = (const float*)d_in[12];
    float* out = (float*)d_out;

    lstm_fused<<<256, 512, 0, stream>>>(x, Wih1, Whh1, bih1, bhh1,
                                        Wih2, Whh2, bih2, bhh2,
                                        Wd1, bd1, Wd2, bd2, out);
}